// Round 4
// baseline (280.818 us; speedup 1.0000x reference)
//
#include <hip/hip_runtime.h>

typedef __bf16 bf16x8 __attribute__((ext_vector_type(8)));
typedef float  f32x4  __attribute__((ext_vector_type(4)));

__device__ __forceinline__ unsigned short f2bf(float f){
  unsigned u = __float_as_uint(f);
  return (unsigned short)((u + 0x7fffu + ((u >> 16) & 1u)) >> 16);  // RNE
}

// ---------------- prep: fuse Wk|Wv -> Wt bf16 [1024 fused cols][512 d], zero accumulators
// fused col f: group gf=f>>4 ; gf even = K-chunk, odd = V-chunk ; src col c=(gf>>1)*16+(f&15)
__global__ void prep_kernel(const float* __restrict__ Wk, const float* __restrict__ Wv,
                            unsigned short* __restrict__ Wt, float* __restrict__ accg){
  int i = blockIdx.x * 256 + threadIdx.x;          // 0..524287
  if (i < 6144) accg[i] = 0.f;                     // accg[4][1024] (KV|Ksum) + pre[4][512]
  int f  = i >> 9, d = i & 511;
  int gf = f >> 4, t = f & 15;
  int c  = (gf >> 1) * 16 + t;                     // col in [0,512) == h*64+hd
  const float* W = (gf & 1) ? Wv : Wk;
  int h = c >> 6, hd = c & 63;
  Wt[i] = f2bf(W[(h * 512 + d) * 64 + hd]);
}

// ---------------- main: 64-row panel, full K=512 staged in LDS ONCE (1 barrier),
// then 4 col-tiles x 16 ksteps, B global->VGPR from L2-resident Wt, 1-step prefetch.
__global__ __launch_bounds__(256, 2) void kv_kernel(const float* __restrict__ x,
    const unsigned short* __restrict__ Wt, const float* __restrict__ bk,
    const float* __restrict__ bv, float* __restrict__ accg){
  __shared__ __align__(16) unsigned short As[64 * 512];   // bf16 x panel  64 KB

  int bid = blockIdx.x;
  int wg  = (bid & 7) * 64 + (bid >> 3);           // XCD swizzle (512 % 8 == 0)
  int row0 = wg << 6;                              // 64-row panel
  int n    = wg >> 7;                              // 128 panels per n
  int tid = threadIdx.x;
  int l = tid & 63, w = tid >> 6;
  int wr = w >> 1, wc = w & 1;                     // wave = 32 rows x 128 cols per col-tile

  // B fragment base: lane l covers Wt row (wc*128 + q*16 + (l&15)), k = ks*32 + (l>>4)*8
  // lanes {l, l+16, l+32, l+48} = same col, contiguous 64 B  -> coalesced from L2
  const unsigned short* Bg = Wt + (size_t)(wc * 128 + (l & 15)) * 512 + (l >> 4) * 8;

  bf16x8 bF[2][8];
  #pragma unroll
  for (int q = 0; q < 8; ++q)                      // prologue: B(ct=0,ks=0) before staging
    bF[0][q] = *(const bf16x8*)(Bg + q * 8192);

  // ---- stage A once: 64 rows x 512 k, fp32->bf16, swizzle byte ^= ((row>>1)&7)<<4
  {
    int rb = w * 16 + (l >> 3);                    // wave covers rows w*16..w*16+15
    int cs = l & 7;
    #pragma unroll
    for (int i = 0; i < 16; ++i){
      int half = i >> 3, jj = i & 7;
      int row  = rb + 8 * half;
      int slot = cs + 8 * jj;                      // 16B slot in [0,64)
      const float* g = x + (size_t)(row0 + row) * 512 + slot * 8;
      float4 f0 = *(const float4*)g;
      float4 f1 = *(const float4*)(g + 4);
      bf16x8 v;
      v[0]=(__bf16)f0.x; v[1]=(__bf16)f0.y; v[2]=(__bf16)f0.z; v[3]=(__bf16)f0.w;
      v[4]=(__bf16)f1.x; v[5]=(__bf16)f1.y; v[6]=(__bf16)f1.z; v[7]=(__bf16)f1.w;
      *(bf16x8*)((char*)As + row * 1024 + ((slot * 16) ^ (((row >> 1) & 7) << 4))) = v;
    }
  }
  __syncthreads();                                 // the ONLY barrier

  const f32x4 vz = {0.f, 0.f, 0.f, 0.f};
  for (int ct = 0; ct < 4; ++ct){                  // 4 col-tiles of 256 fused cols
    f32x4 acc[2][8];
    #pragma unroll
    for (int m = 0; m < 2; ++m)
      #pragma unroll
      for (int q = 0; q < 8; ++q) acc[m][q] = vz;

    #pragma unroll
    for (int ks = 0; ks < 16; ++ks){
      // prefetch next kstep's B (1-step double buffer; indices all compile-time)
      if (ks < 15){
        const unsigned short* bg = Bg + ct * 131072 + (ks + 1) * 32;
        #pragma unroll
        for (int q = 0; q < 8; ++q)
          bF[(ks + 1) & 1][q] = *(const bf16x8*)(bg + q * 8192);
      } else if (ct < 3){
        const unsigned short* bg = Bg + (ct + 1) * 131072;
        #pragma unroll
        for (int q = 0; q < 8; ++q)
          bF[0][q] = *(const bf16x8*)(bg + q * 8192);
      }
      bf16x8 aF[2];
      int kb = ks * 64 + (l >> 4) * 16;
      #pragma unroll
      for (int m = 0; m < 2; ++m){
        int row = wr * 32 + m * 16 + (l & 15);
        aF[m] = *(const bf16x8*)((const char*)As + row * 1024 + (kb ^ (((row >> 1) & 7) << 4)));
      }
      #pragma unroll
      for (int m = 0; m < 2; ++m)
        #pragma unroll
        for (int q = 0; q < 8; ++q)
          acc[m][q] = __builtin_amdgcn_mfma_f32_16x16x32_bf16(aF[m], bF[ks & 1][q], acc[m][q], 0, 0, 0);
    }

    // epilogue per col-tile: frag pairs (2p, 2p+1) = (K cols, V cols), same src col
    #pragma unroll
    for (int p = 0; p < 4; ++p){
      int c = (ct * 8 + wc * 4 + p) * 16 + (l & 15);   // source col in [0,512)
      float bkc = bk[c], bvc = bv[c];
      float sKV = 0.f, sK = 0.f;
      #pragma unroll
      for (int m = 0; m < 2; ++m)
        #pragma unroll
        for (int r = 0; r < 4; ++r){
          float kp  = acc[m][2 * p][r] + bkc;
          float kvv = kp > 0.f ? kp + 1.f : __expf(kp);  // elu(x)+1
          sKV += kvv * (acc[m][2 * p + 1][r] + bvc);
          sK  += kvv;
        }
      sKV += __shfl_xor(sKV, 16); sKV += __shfl_xor(sKV, 32);
      sK  += __shfl_xor(sK , 16); sK  += __shfl_xor(sK , 32);
      if ((l >> 4) == 0){
        atomicAdd(&accg[n * 1024 + c],       sKV);
        atomicAdd(&accg[n * 1024 + 512 + c], sK);
      }
    }
  }
}

// ---------------- finalize1: pre[n,o] += sum_{c in 8-chunk} (KV/Ksum)[c] * Wo[c,o]
__global__ void fin1_kernel(const float* __restrict__ accg, const float* __restrict__ Wo,
                            float* __restrict__ pre){
  int b = blockIdx.x;                              // 256 = 4 n * 64 c-chunks
  int n = b >> 6, cb = b & 63;
  int t = threadIdx.x;
  __shared__ float ov[8];
  if (t < 8){ int c = cb * 8 + t; ov[t] = accg[n * 1024 + c] / accg[n * 1024 + 512 + c]; }
  __syncthreads();
  float s0 = 0.f, s1 = 0.f;
  #pragma unroll
  for (int j = 0; j < 8; ++j){
    int c = cb * 8 + j;
    s0 += ov[j] * Wo[c * 512 + t];
    s1 += ov[j] * Wo[c * 512 + 256 + t];
  }
  atomicAdd(&pre[n * 512 + t],       s0);
  atomicAdd(&pre[n * 512 + 256 + t], s1);
}

// ---------------- bcast: out[n,s,:] = gelu(pre[n,:] + bo)  (gelu computed once per block)
__global__ void bcast_kernel(const float* __restrict__ pre, const float* __restrict__ bo,
                             float4* __restrict__ out){
  __shared__ float row[512];
  int bid = blockIdx.x;                            // 2048 = 4 n * 512 chunks
  int n = bid >> 9, bc = bid & 511;
  int t = threadIdx.x;
  #pragma unroll
  for (int j = 0; j < 2; ++j){
    int o = t + j * 256;
    float s = pre[n * 512 + o] + bo[o];
    float u = 0.7978845608028654f * (s + 0.044715f * s * s * s);
    row[o] = 0.5f * s * (1.f + tanhf(u));
  }
  __syncthreads();
  float4 v = ((const float4*)row)[t & 127];        // value is iteration-invariant
  float4* dst = out + ((size_t)n << 20) + bc * 2048;
  #pragma unroll
  for (int it = 0; it < 8; ++it)
    dst[it * 256 + t] = v;                         // 4 KB coalesced per iter
}

extern "C" void kernel_launch(void* const* d_in, const int* in_sizes, int n_in,
                              void* d_out, int out_size, void* d_ws, size_t ws_size,
                              hipStream_t stream){
  const float* x  = (const float*)d_in[0];
  // d_in[1]=Wq, d_in[2]=bq  — provably irrelevant (eps/(Q*Ksum) ~ 3e-8 relative)
  const float* Wk = (const float*)d_in[3];
  const float* bk = (const float*)d_in[4];
  const float* Wv = (const float*)d_in[5];
  const float* bv = (const float*)d_in[6];
  const float* Wo = (const float*)d_in[7];
  const float* bo = (const float*)d_in[8];
  float* out = (float*)d_out;

  char* ws = (char*)d_ws;
  unsigned short* Wt = (unsigned short*)ws;            // 1 MB  bf16 [1024][512]
  float* accg = (float*)(ws + (1 << 20));              // 16 KB [4][1024] KV|Ksum
  float* pre  = (float*)(ws + (1 << 20) + 16384);      // 8 KB  [4][512] pre-gelu

  prep_kernel <<<2048, 256, 0, stream>>>(Wk, Wv, Wt, accg);
  kv_kernel   <<<512, 256, 0, stream>>>(x, Wt, bk, bv, accg);
  fin1_kernel <<<256, 256, 0, stream>>>(accg, Wo, pre);
  bcast_kernel<<<2048, 256, 0, stream>>>(pre, bo, (float4*)out);
}

// Round 5
// 240.954 us; speedup vs baseline: 1.1654x; 1.1654x over previous
//
#include <hip/hip_runtime.h>

typedef __bf16 bf16x8 __attribute__((ext_vector_type(8)));
typedef float  f32x4  __attribute__((ext_vector_type(4)));

#define LDS_AS(p)  ((__attribute__((address_space(3))) void*)(p))
#define GLB_AS(p)  ((const __attribute__((address_space(1))) void*)(p))

__device__ __forceinline__ unsigned short f2bf(float f){
  unsigned u = __float_as_uint(f);
  return (unsigned short)((u + 0x7fffu + ((u >> 16) & 1u)) >> 16);  // RNE
}

// ---------------- prep: fuse Wk|Wv -> Wt bf16 [1024 fused cols][512 d], zero accg+cnt
// fused col f: group gf=f>>4 ; gf even = K-chunk, odd = V-chunk ; src col c=(gf>>1)*16+(f&15)
__global__ void prep_kernel(const float* __restrict__ Wk, const float* __restrict__ Wv,
                            unsigned short* __restrict__ Wt, float* __restrict__ accg){
  int i = blockIdx.x * 256 + threadIdx.x;          // 0..524287
  if (i < 6144) accg[i] = 0.f;                     // accg[4][1024] + cnt + rows region
  int f  = i >> 9, d = i & 511;
  int gf = f >> 4, t = f & 15;
  int c  = (gf >> 1) * 16 + t;                     // col in [0,512) == h*64+hd
  const float* W = (gf & 1) ? Wv : Wk;
  int h = c >> 6, hd = c & 63;
  Wt[i] = f2bf(W[(h * 512 + d) * 64 + hd]);
}

// ---------------- main: 128x256 tile, BK=64, 4 waves of 64x128 (acc 4x8).
// A reg-staged fp32->bf16 swizzled ds_write; B global_load_lds from Wt.
// Last block (atomic counter) computes fin: O=KV/Ksum, O@Wo+bo, gelu -> rows.
__global__ __launch_bounds__(256, 2) void kv_kernel(const float* __restrict__ x,
    const unsigned short* __restrict__ Wt, const float* __restrict__ bk,
    const float* __restrict__ bv, float* __restrict__ accg,
    const float* __restrict__ Wo, const float* __restrict__ bo,
    float* __restrict__ rows, int* __restrict__ cnt){
  __shared__ __align__(16) unsigned short As[128 * 64];   // 16 KB
  __shared__ __align__(16) unsigned short Bs[256 * 64];   // 32 KB
  __shared__ int lastBlk;

  int bid = blockIdx.x;
  int wg  = (bid & 7) * 128 + (bid >> 3);          // XCD swizzle (1024 % 8 == 0)
  int rowp = wg >> 2, colp = wg & 3;               // 256 row-panels x 4 col-panels
  int row0 = rowp << 7;
  int n    = rowp >> 6;
  int tid = threadIdx.x;
  int l = tid & 63, w = tid >> 6;
  int wr = w >> 1, wc = w & 1;                     // wave = 64 rows x 128 fused cols

  const f32x4 vz = {0.f, 0.f, 0.f, 0.f};
  f32x4 acc[4][8];
  #pragma unroll
  for (int m = 0; m < 4; ++m)
    #pragma unroll
    for (int q = 0; q < 8; ++q) acc[m][q] = vz;

  // A staging: lane covers row rA+8j (j=0..3), 16B slot cc (8 fp32 elems)
  int rA = w * 32 + (l >> 3);
  int cc = l & 7;
  const float* xg = x + (size_t)(row0 + rA) * 512 + cc * 8;

  float4 fA[4][2];
  #pragma unroll
  for (int j = 0; j < 4; ++j){                     // prologue: kt=0 A loads
    const float* g = xg + (size_t)j * 8 * 512;
    fA[j][0] = *(const float4*)g;
    fA[j][1] = *(const float4*)(g + 4);
  }

  for (int kt = 0; kt < 8; ++kt){
    if (kt) __syncthreads();                       // prev-iter LDS reads done
    // ---- stage A: cvt + swizzled ds_write_b128 (row stride 128B, byte ^= ((r>>1)&7)<<4)
    #pragma unroll
    for (int j = 0; j < 4; ++j){
      int r  = rA + 8 * j;
      int sw = ((r >> 1) & 7) << 4;
      float4 f0 = fA[j][0], f1 = fA[j][1];
      bf16x8 v;
      v[0]=(__bf16)f0.x; v[1]=(__bf16)f0.y; v[2]=(__bf16)f0.z; v[3]=(__bf16)f0.w;
      v[4]=(__bf16)f1.x; v[5]=(__bf16)f1.y; v[6]=(__bf16)f1.z; v[7]=(__bf16)f1.w;
      *(bf16x8*)((char*)As + r * 128 + ((cc * 16) ^ sw)) = v;
    }
    // ---- stage B: 32 KB via global_load_lds, linear dest, inverse-swizzled source
    #pragma unroll
    for (int i = 0; i < 8; ++i){
      int L   = (w * 8 + i) * 1024 + l * 16;
      int col = L >> 7;
      int s   = L & 127;
      int sb  = kt * 128 + (s ^ (((col >> 1) & 7) << 4));
      const char* g = (const char*)Wt + (size_t)(colp * 256 + col) * 1024 + sb;
      char* lb = (char*)Bs + (size_t)(w * 8 + i) * 1024;   // wave-uniform base
      __builtin_amdgcn_global_load_lds(GLB_AS(g), LDS_AS(lb), 16, 0, 0);
    }
    __syncthreads();                               // drains B loads + A writes

    if (kt < 7){                                   // prefetch next A tile -> regs
      const float* gk = xg + (kt + 1) * 64;        // hides under MFMA phase
      #pragma unroll
      for (int j = 0; j < 4; ++j){
        const float* g = gk + (size_t)j * 8 * 512;
        fA[j][0] = *(const float4*)g;
        fA[j][1] = *(const float4*)(g + 4);
      }
    }

    // ---- compute: per kk: 4+8 ds_read_b128 + 32 MFMA
    #pragma unroll
    for (int kk = 0; kk < 2; ++kk){
      bf16x8 aF[4], bF[8];
      int kb = kk * 64 + (l >> 4) * 16;
      #pragma unroll
      for (int m = 0; m < 4; ++m){
        int row = wr * 64 + m * 16 + (l & 15);
        aF[m] = *(const bf16x8*)((const char*)As + row * 128 + (kb ^ (((row >> 1) & 7) << 4)));
      }
      #pragma unroll
      for (int q = 0; q < 8; ++q){
        int col = wc * 128 + q * 16 + (l & 15);
        bF[q] = *(const bf16x8*)((const char*)Bs + col * 128 + (kb ^ (((col >> 1) & 7) << 4)));
      }
      #pragma unroll
      for (int m = 0; m < 4; ++m)
        #pragma unroll
        for (int q = 0; q < 8; ++q)
          acc[m][q] = __builtin_amdgcn_mfma_f32_16x16x32_bf16(aF[m], bF[q], acc[m][q], 0, 0, 0);
    }
  }

  // epilogue: frag pairs (2p, 2p+1) = (K cols, V cols) at identical (row, src col)
  #pragma unroll
  for (int p = 0; p < 4; ++p){
    int c = (colp * 8 + wc * 4 + p) * 16 + (l & 15);   // source col in [0,512)
    float bkc = bk[c], bvc = bv[c];
    float sKV = 0.f, sK = 0.f;
    #pragma unroll
    for (int m = 0; m < 4; ++m)
      #pragma unroll
      for (int r = 0; r < 4; ++r){
        float kp  = acc[m][2 * p][r] + bkc;
        float kvv = kp > 0.f ? kp + 1.f : __expf(kp);  // elu(x)+1
        sKV += kvv * (acc[m][2 * p + 1][r] + bvc);
        sK  += kvv;
      }
    sKV += __shfl_xor(sKV, 16); sKV += __shfl_xor(sKV, 32);
    sK  += __shfl_xor(sK , 16); sK  += __shfl_xor(sK , 32);
    if ((l >> 4) == 0){
      atomicAdd(&accg[n * 1024 + c],       sKV);
      atomicAdd(&accg[n * 1024 + 512 + c], sK);
    }
  }

  // ---- last-block finalize
  __syncthreads();                                 // all waves' atomics drained (vmcnt 0)
  if (tid == 0){
    __threadfence();
    int prev = __hip_atomic_fetch_add(cnt, 1, __ATOMIC_ACQ_REL, __HIP_MEMORY_SCOPE_AGENT);
    lastBlk = (prev == (int)gridDim.x - 1);
  }
  __syncthreads();
  if (!lastBlk) return;

  float* ov = (float*)As;                          // 8 KB reuse: ov[4][512]
  #pragma unroll
  for (int n2 = 0; n2 < 4; ++n2)
    #pragma unroll
    for (int j = 0; j < 2; ++j){
      int c = tid + j * 256;
      ov[n2 * 512 + c] = accg[n2 * 1024 + c] / accg[n2 * 1024 + 512 + c];
    }
  __syncthreads();
  float s[4][2] = {{0.f,0.f},{0.f,0.f},{0.f,0.f},{0.f,0.f}};
  for (int c = 0; c < 512; ++c){
    float w0 = Wo[c * 512 + tid], w1 = Wo[c * 512 + 256 + tid];
    #pragma unroll
    for (int n2 = 0; n2 < 4; ++n2){
      float o = ov[n2 * 512 + c];
      s[n2][0] += o * w0;
      s[n2][1] += o * w1;
    }
  }
  #pragma unroll
  for (int n2 = 0; n2 < 4; ++n2)
    #pragma unroll
    for (int j = 0; j < 2; ++j){
      int o = tid + j * 256;
      float v = s[n2][j] + bo[o];
      float u = 0.7978845608028654f * (v + 0.044715f * v * v * v);
      rows[n2 * 512 + o] = 0.5f * v * (1.f + tanhf(u));
    }
}

// ---------------- bcast: out[n,s,:] = rows[n,:]
__global__ void bcast_kernel(const float* __restrict__ rows, float4* __restrict__ out){
  __shared__ float4 row4[128];
  int bid = blockIdx.x;                            // 2048 = 4 n * 512 chunks
  int n = bid >> 9, bc = bid & 511;
  int t = threadIdx.x;
  if (t < 128) row4[t] = ((const float4*)(rows + n * 512))[t];
  __syncthreads();
  float4 v = row4[t & 127];
  float4* dst = out + ((size_t)n << 20) + bc * 2048;
  #pragma unroll
  for (int it = 0; it < 8; ++it)
    dst[it * 256 + t] = v;                         // 4 KB coalesced per iter
}

extern "C" void kernel_launch(void* const* d_in, const int* in_sizes, int n_in,
                              void* d_out, int out_size, void* d_ws, size_t ws_size,
                              hipStream_t stream){
  const float* x  = (const float*)d_in[0];
  // d_in[1]=Wq, d_in[2]=bq  — provably irrelevant (eps/(Q*Ksum) ~ 3e-8 relative)
  const float* Wk = (const float*)d_in[3];
  const float* bk = (const float*)d_in[4];
  const float* Wv = (const float*)d_in[5];
  const float* bv = (const float*)d_in[6];
  const float* Wo = (const float*)d_in[7];
  const float* bo = (const float*)d_in[8];
  float* out = (float*)d_out;

  char* ws = (char*)d_ws;
  unsigned short* Wt = (unsigned short*)ws;            // 1 MB   bf16 [1024][512]
  float* accg = (float*)(ws + (1 << 20));              // 16 KB  [4][1024] KV|Ksum
  int*   cnt  = (int*)(ws + (1 << 20) + 16384);        // 4 B    done-counter
  float* rows = (float*)(ws + (1 << 20) + 20480);      // 8 KB   [4][512] post-gelu

  prep_kernel <<<2048, 256, 0, stream>>>(Wk, Wv, Wt, accg);
  kv_kernel   <<<1024, 256, 0, stream>>>(x, Wt, bk, bv, accg, Wo, bo, rows, cnt);
  bcast_kernel<<<2048, 256, 0, stream>>>(rows, (float4*)out);
}